// Round 2
// baseline (652.509 us; speedup 1.0000x reference)
//
#include <hip/hip_runtime.h>

// Problem constants
#define NROWS 8192
#define DDIM  512
#define MEXP  2048
#define BDIM  4
#define KTOP  8

typedef unsigned long long ull;

// d_out layout (floats): h_sparse [0,262144), idx [262144,327680), 7 scalars at 327680
#define OUT_IDX     262144
#define OUT_SCAL    327680

// d_ws layout (bytes)
#define WS_VT_BYTES (2048u * 512u * 16u)   // 16 MiB: Vt[m][d] as float4 (b-dim)
#define WS_ESUM_OFF WS_VT_BYTES            // 2048 f32
#define WS_CNT_OFF  (WS_VT_BYTES + 8192u)  // 2048 u32
#define WS_SCAL_OFF (WS_VT_BYTES + 16384u) // [0]=captured_sum [1]=resid_sum [2]=recon_sum

// ---------------------------------------------------------------------------
// Kernel 1: wave-per-row energy + top-8. 1024 blocks x 256 thr; each wave
// handles 2 rows. Per-lane sorted top-8 of packed keys, butterfly argmax.
// ---------------------------------------------------------------------------
__global__ __launch_bounds__(256) void energy_topk_kernel(
    const float* __restrict__ h_all, float* __restrict__ out,
    float* __restrict__ expert_sum, unsigned int* __restrict__ counts_g,
    float* __restrict__ scalars)
{
    __shared__ float s_es[MEXP];
    __shared__ float s_cap[4];

    const int t    = threadIdx.x;
    const int lane = t & 63;
    const int wid  = t >> 6;

    for (int j = t; j < MEXP; j += 256) s_es[j] = 0.f;
    __syncthreads();

    float esum[32];
#pragma unroll
    for (int j = 0; j < 32; ++j) esum[j] = 0.f;
    float capw = 0.f;

    const int gw = blockIdx.x * 4 + wid;   // global wave id, 4096 waves

    for (int r = 0; r < 2; ++r) {
        const int n = gw * 2 + r;
        const float4* __restrict__ hrow4 =
            (const float4*)(h_all + (size_t)n * (MEXP * BDIM));

        ull k[8];
#pragma unroll
        for (int j = 0; j < 8; ++j) k[j] = 0ull;

        // stream 32 experts/lane in 4 chunks of 8 (8 KB contiguous per chunk)
#pragma unroll
        for (int c = 0; c < 4; ++c) {
            float4 hv[8];
#pragma unroll
            for (int i = 0; i < 8; ++i)
                hv[i] = hrow4[lane + 64 * (8 * c + i)];
#pragma unroll
            for (int i = 0; i < 8; ++i) {
                const int m = lane + 64 * (8 * c + i);
                const float4 h = hv[i];
                // bit-exact numpy f32 sequential sum (no FMA contraction)
                float e = __fadd_rn(__fadd_rn(__fadd_rn(__fmul_rn(h.x, h.x),
                                                        __fmul_rn(h.y, h.y)),
                                              __fmul_rn(h.z, h.z)),
                                    __fmul_rn(h.w, h.w));
                esum[8 * c + i] += e;
                ull key = ((ull)__float_as_uint(e) << 32) |
                          (ull)(0xFFFFFFFFu - (unsigned)m);
                // branchless sorted insert (descending)
#pragma unroll
                for (int j = 0; j < 8; ++j) {
                    const ull mx = (key > k[j]) ? key : k[j];
                    const ull mn = (key > k[j]) ? k[j] : key;
                    k[j] = mx;
                    key  = mn;
                }
            }
        }

        // 8 rounds of wave-wide argmax over k[0] (keys unique -> one owner)
        int mym = 0;
#pragma unroll
        for (int round = 0; round < 8; ++round) {
            ull w = k[0];
#pragma unroll
            for (int off = 1; off < 64; off <<= 1) {
                const ull o = __shfl_xor(w, off, 64);
                w = (o > w) ? o : w;
            }
            const int m = (int)(0xFFFFFFFFu - (unsigned)(w & 0xFFFFFFFFull));
            if (lane == round) mym = m;
            if (lane == 0) capw += __uint_as_float((unsigned)(w >> 32));
            const bool own = (k[0] == w);
#pragma unroll
            for (int j = 0; j < 7; ++j) k[j] = own ? k[j + 1] : k[j];
            if (own) k[7] = 0ull;
        }

        if (lane < KTOP) {
            const float4 hv = hrow4[mym];                      // L1/L2 hit
            ((float4*)out)[(size_t)n * KTOP + lane] = hv;      // h_sparse
            out[OUT_IDX + (size_t)n * KTOP + lane] = (float)mym;
            atomicAdd(&counts_g[mym], 1u);
        }
    }

    // block-level reduce of expert energy sums
#pragma unroll
    for (int j = 0; j < 32; ++j)
        atomicAdd(&s_es[lane + 64 * j], esum[j]);              // ds_add_f32
    if (lane == 0) s_cap[wid] = capw;
    __syncthreads();
    for (int j = t; j < MEXP; j += 256)
        atomicAdd(&expert_sum[j], s_es[j]);
    if (t == 0)
        atomicAdd(&scalars[0], s_cap[0] + s_cap[1] + s_cap[2] + s_cap[3]);
}

// ---------------------------------------------------------------------------
// Kernel 2: transpose V (D,M,B) -> Vt (M,D,B), float4 elements over b
// ---------------------------------------------------------------------------
__global__ __launch_bounds__(256) void transpose_v_kernel(
    const float4* __restrict__ V, float4* __restrict__ Vt)
{
    __shared__ float4 tile[32][33];
    const int bx = blockIdx.x;       // m tile: 0..63
    const int by = blockIdx.y;       // d tile: 0..15
    const int tx = threadIdx.x & 31;
    const int ty = threadIdx.x >> 5; // 0..7

#pragma unroll
    for (int i = 0; i < 4; ++i) {
        const int d = by * 32 + ty + i * 8;
        const int m = bx * 32 + tx;
        tile[ty + i * 8][tx] = V[(size_t)d * MEXP + m];
    }
    __syncthreads();
#pragma unroll
    for (int i = 0; i < 4; ++i) {
        const int m = bx * 32 + ty + i * 8;
        const int d = by * 32 + tx;
        Vt[(size_t)m * DDIM + d] = tile[tx][ty + i * 8];
    }
}

// ---------------------------------------------------------------------------
// Kernel 3: x_hat per row — all 16 Vt loads hoisted (full MLP), coalesced
// d-mapping (t, t+256).
// ---------------------------------------------------------------------------
__global__ __launch_bounds__(256) void recon_kernel(
    const float* __restrict__ x_flat, const float* __restrict__ out_ro,
    const float4* __restrict__ Vt, float* __restrict__ scalars)
{
    __shared__ float4 s_h[KTOP];
    __shared__ int    s_m[KTOP];
    __shared__ float  s_lr[4], s_lh[4];

    const int n    = blockIdx.x;
    const int t    = threadIdx.x;
    const int lane = t & 63;
    const int wid  = t >> 6;

    if (t < KTOP) {
        s_m[t] = (int)out_ro[OUT_IDX + (size_t)n * KTOP + t];
        s_h[t] = ((const float4*)out_ro)[(size_t)n * KTOP + t];
    }
    __syncthreads();

    float4 v0[KTOP], v1[KTOP];
#pragma unroll
    for (int k = 0; k < KTOP; ++k) {
        const size_t o = (size_t)s_m[k] * DDIM;
        v0[k] = Vt[o + t];          // lanes -> consecutive float4: coalesced
        v1[k] = Vt[o + t + 256];
    }

    float xh0 = 0.f, xh1 = 0.f;
#pragma unroll
    for (int k = 0; k < KTOP; ++k) {
        const float4 hv = s_h[k];
        xh0 += v0[k].x * hv.x + v0[k].y * hv.y + v0[k].z * hv.z + v0[k].w * hv.w;
        xh1 += v1[k].x * hv.x + v1[k].y * hv.y + v1[k].z * hv.z + v1[k].w * hv.w;
    }

    const float x0 = x_flat[(size_t)n * DDIM + t];
    const float x1 = x_flat[(size_t)n * DDIM + t + 256];
    const float r0 = x0 - xh0, r1 = x1 - xh1;
    float lr = r0 * r0 + r1 * r1;
    float lh = xh0 * xh0 + xh1 * xh1;

#pragma unroll
    for (int off = 32; off > 0; off >>= 1) {
        lr += __shfl_down(lr, off, 64);
        lh += __shfl_down(lh, off, 64);
    }
    if (lane == 0) { s_lr[wid] = lr; s_lh[wid] = lh; }
    __syncthreads();
    if (t == 0) {
        atomicAdd(&scalars[1], s_lr[0] + s_lr[1] + s_lr[2] + s_lr[3]);
        atomicAdd(&scalars[2], s_lh[0] + s_lh[1] + s_lh[2] + s_lh[3]);
    }
}

// ---------------------------------------------------------------------------
// Kernel 4: finalize scalars
// ---------------------------------------------------------------------------
__device__ __forceinline__ double block_reduce_d(double v, double* s4,
                                                 int lane, int wid)
{
#pragma unroll
    for (int off = 32; off > 0; off >>= 1) v += __shfl_down(v, off, 64);
    if (lane == 0) s4[wid] = v;
    __syncthreads();
    const double r = s4[0] + s4[1] + s4[2] + s4[3];
    __syncthreads();
    return r;
}

__global__ __launch_bounds__(256) void finalize_kernel(
    const float* __restrict__ expert_sum, const unsigned int* __restrict__ counts,
    const float* __restrict__ scalars, float* __restrict__ out)
{
    __shared__ double s4[4];
    const int t = threadIdx.x, lane = t & 63, wid = t >> 6;

    double avg[8];
    double tot = 0.0;
#pragma unroll
    for (int j = 0; j < 8; ++j) {
        avg[j] = (double)expert_sum[t + 256 * j] / (double)NROWS;
        tot += avg[j];
    }
    double denom = block_reduce_d(tot, s4, lane, wid);
    denom = (denom > 1e-8) ? denom : 1e-8;

    double entl = 0.0;
#pragma unroll
    for (int j = 0; j < 8; ++j) {
        double p = avg[j] / denom;
        p = (p > 1e-8) ? p : 1e-8;
        entl -= p * log(p);
    }
    const double entropy = block_reduce_d(entl, s4, lane, wid) / log(2048.0);

    double lowl = 0.0, deadl = 0.0;
    const float expected = (float)KTOP / (float)MEXP * (float)NROWS; // 32
#pragma unroll
    for (int j = 0; j < 8; ++j) {
        const float c = (float)counts[t + 256 * j];
        if (c <= 0.1f * expected)  lowl  += 1.0;
        if (c <= 0.01f * expected) deadl += 1.0;
    }
    const double low  = block_reduce_d(lowl, s4, lane, wid);
    const double dead = block_reduce_d(deadl, s4, lane, wid);

    if (t == 0) {
        const double captured = (double)scalars[0] / (double)NROWS;
        const double uncap    = (double)scalars[1] / (double)NROWS;
        const double recon    = (double)scalars[2] / (double)NROWS;
        out[OUT_SCAL + 0] = (float)captured;
        out[OUT_SCAL + 1] = (float)recon;
        out[OUT_SCAL + 2] = (float)uncap;
        out[OUT_SCAL + 3] = (float)entropy;
        out[OUT_SCAL + 4] = (float)(uncap + 0.01 * (1.0 - entropy));
        out[OUT_SCAL + 5] = (float)low;
        out[OUT_SCAL + 6] = (float)dead;
    }
}

// ---------------------------------------------------------------------------
extern "C" void kernel_launch(void* const* d_in, const int* in_sizes, int n_in,
                              void* d_out, int out_size, void* d_ws, size_t ws_size,
                              hipStream_t stream)
{
    const float* x = (const float*)d_in[0];
    const float* h = (const float*)d_in[1];
    const float* V = (const float*)d_in[2];
    float* out = (float*)d_out;
    char*  ws  = (char*)d_ws;

    float4*       Vt         = (float4*)ws;
    float*        expert_sum = (float*)(ws + WS_ESUM_OFF);
    unsigned int* counts     = (unsigned int*)(ws + WS_CNT_OFF);
    float*        scalars    = (float*)(ws + WS_SCAL_OFF);

    // zero accumulators (ws is poisoned 0xAA before every call)
    hipMemsetAsync(ws + WS_ESUM_OFF, 0, 16384 + 64, stream);

    transpose_v_kernel<<<dim3(64, 16), 256, 0, stream>>>((const float4*)V, Vt);
    energy_topk_kernel<<<1024, 256, 0, stream>>>(h, out, expert_sum, counts,
                                                 scalars);
    recon_kernel<<<NROWS, 256, 0, stream>>>(x, out, Vt, scalars);
    finalize_kernel<<<1, 256, 0, stream>>>(expert_sum, counts, scalars, out);
}

// Round 3
// 643.315 us; speedup vs baseline: 1.0143x; 1.0143x over previous
//
#include <hip/hip_runtime.h>

// Problem constants
#define NROWS 8192
#define DDIM  512
#define MEXP  2048
#define BDIM  4
#define KTOP  8

typedef unsigned long long ull;

// d_out layout (floats): h_sparse [0,262144), idx [262144,327680), 7 scalars at 327680
#define OUT_IDX     262144
#define OUT_SCAL    327680

// d_ws layout (bytes)
#define WS_VT_BYTES (2048u * 512u * 16u)   // 16 MiB: Vt[m][d] as float4 (b-dim)
#define WS_ESUM_OFF WS_VT_BYTES            // 2048 f32
#define WS_CNT_OFF  (WS_VT_BYTES + 8192u)  // 2048 u32
#define WS_SCAL_OFF (WS_VT_BYTES + 16384u) // [0]=captured_sum [1]=resid_sum [2]=recon_sum

typedef __attribute__((address_space(1))) unsigned int gu32;
typedef __attribute__((address_space(3))) unsigned int lu32;

// ---------------------------------------------------------------------------
// Kernel 1: wave-per-row energy + top-8 via global_load_lds streaming.
// Block = 128 thr (2 waves), LDS = 2 x 32KB row staging. 1024 blocks,
// 4 rows per wave. 32 async 1KB loads in flight per wave -> HBM-bound.
// ---------------------------------------------------------------------------
__global__ __launch_bounds__(128) void energy_topk_kernel(
    const float* __restrict__ h_all, float* __restrict__ out,
    float* __restrict__ expert_sum, unsigned int* __restrict__ counts_g,
    float* __restrict__ scalars)
{
    __shared__ float4 stage[2][MEXP];     // 64 KB: one full row per wave

    const int t    = threadIdx.x;
    const int lane = t & 63;
    const int wid  = t >> 6;              // 0..1
    float4* buf = stage[wid];

    float esum[32];
#pragma unroll
    for (int j = 0; j < 32; ++j) esum[j] = 0.f;
    float capw = 0.f;

    const int gwave = blockIdx.x * 2 + wid;      // 2048 waves total

    for (int r = 0; r < 4; ++r) {
        const int n = gwave * 4 + r;
        const float* grow = h_all + (size_t)n * (MEXP * BDIM);

        // issue 32 direct-to-LDS 16B/lane loads (1 KB per instruction)
#pragma unroll
        for (int i = 0; i < 32; ++i) {
            __builtin_amdgcn_global_load_lds(
                (gu32*)(grow) + lane * 4 + i * 256,
                (lu32*)((unsigned int*)buf) + i * 256,
                16, 0, 0);
        }
        __builtin_amdgcn_s_waitcnt(0x0F70);      // vmcnt(0); lgkm/exp don't-care

        ull k[8];
#pragma unroll
        for (int j = 0; j < 8; ++j) k[j] = 0ull;

#pragma unroll
        for (int i = 0; i < 32; ++i) {
            const int m = lane + 64 * i;
            const float4 h = buf[m];             // ds_read_b128, 2-way alias
            // bit-exact numpy f32 sequential sum (no FMA contraction)
            float e = __fadd_rn(__fadd_rn(__fadd_rn(__fmul_rn(h.x, h.x),
                                                    __fmul_rn(h.y, h.y)),
                                          __fmul_rn(h.z, h.z)),
                                __fmul_rn(h.w, h.w));
            esum[i] += e;
            ull key = ((ull)__float_as_uint(e) << 32) |
                      (ull)(0xFFFFFFFFu - (unsigned)m);
            // branchless sorted insert (descending); ties -> lower index
#pragma unroll
            for (int j = 0; j < 8; ++j) {
                const ull mx = (key > k[j]) ? key : k[j];
                const ull mn = (key > k[j]) ? k[j] : key;
                k[j] = mx;
                key  = mn;
            }
        }

        // 8 rounds of wave-wide argmax over k[0] (keys unique)
        int mym = 0;
#pragma unroll
        for (int round = 0; round < 8; ++round) {
            ull w = k[0];
#pragma unroll
            for (int off = 1; off < 64; off <<= 1) {
                const ull o = __shfl_xor(w, off, 64);
                w = (o > w) ? o : w;
            }
            const int m = (int)(0xFFFFFFFFu - (unsigned)(w & 0xFFFFFFFFull));
            if (lane == round) mym = m;
            if (lane == 0) capw += __uint_as_float((unsigned)(w >> 32));
            const bool own = (k[0] == w);
#pragma unroll
            for (int j = 0; j < 7; ++j) k[j] = own ? k[j + 1] : k[j];
            if (own) k[7] = 0ull;
        }

        if (lane < KTOP) {
            const float4 hv = buf[mym];                        // LDS gather
            ((float4*)out)[(size_t)n * KTOP + lane] = hv;      // h_sparse
            out[OUT_IDX + (size_t)n * KTOP + lane] = (float)mym;
            atomicAdd(&counts_g[mym], 1u);
        }
    }

    // flush per-lane expert energy sums (addresses distinct per lane)
#pragma unroll
    for (int j = 0; j < 32; ++j)
        atomicAdd(&expert_sum[lane + 64 * j], esum[j]);
    if (lane == 0) atomicAdd(&scalars[0], capw);
}

// ---------------------------------------------------------------------------
// Kernel 2: transpose V (D,M,B) -> Vt (M,D,B), float4 elements over b
// ---------------------------------------------------------------------------
__global__ __launch_bounds__(256) void transpose_v_kernel(
    const float4* __restrict__ V, float4* __restrict__ Vt)
{
    __shared__ float4 tile[32][33];
    const int bx = blockIdx.x;       // m tile: 0..63
    const int by = blockIdx.y;       // d tile: 0..15
    const int tx = threadIdx.x & 31;
    const int ty = threadIdx.x >> 5; // 0..7

#pragma unroll
    for (int i = 0; i < 4; ++i) {
        const int d = by * 32 + ty + i * 8;
        const int m = bx * 32 + tx;
        tile[ty + i * 8][tx] = V[(size_t)d * MEXP + m];
    }
    __syncthreads();
#pragma unroll
    for (int i = 0; i < 4; ++i) {
        const int m = bx * 32 + ty + i * 8;
        const int d = by * 32 + tx;
        Vt[(size_t)m * DDIM + d] = tile[tx][ty + i * 8];
    }
}

// ---------------------------------------------------------------------------
// Kernel 3: x_hat per row. All 18 loads issued BEFORE a __syncthreads():
// loads cannot sink past s_barrier and the backend drains vmcnt(0) before
// it -> guaranteed 18 loads in flight per thread batch (MLP fix).
// ---------------------------------------------------------------------------
__global__ __launch_bounds__(256) void recon_kernel(
    const float* __restrict__ x_flat, const float* __restrict__ out_ro,
    const float4* __restrict__ Vt, float* __restrict__ scalars)
{
    __shared__ float4 s_h[KTOP];
    __shared__ int    s_m[KTOP];
    __shared__ float  s_lr[4], s_lh[4];

    const int n    = blockIdx.x;
    const int t    = threadIdx.x;
    const int lane = t & 63;
    const int wid  = t >> 6;

    if (t < KTOP) {
        s_m[t] = (int)out_ro[OUT_IDX + (size_t)n * KTOP + t];
        s_h[t] = ((const float4*)out_ro)[(size_t)n * KTOP + t];
    }
    __syncthreads();

    float4 v0[KTOP], v1[KTOP];
#pragma unroll
    for (int k = 0; k < KTOP; ++k) {
        const size_t o = (size_t)s_m[k] * DDIM;
        v0[k] = Vt[o + t];          // lanes -> consecutive float4: coalesced
        v1[k] = Vt[o + t + 256];
    }
    const float x0 = x_flat[(size_t)n * DDIM + t];
    const float x1 = x_flat[(size_t)n * DDIM + t + 256];
    __syncthreads();                // pins all 18 loads above; vmcnt(0) drain

    float xh0 = 0.f, xh1 = 0.f;
#pragma unroll
    for (int k = 0; k < KTOP; ++k) {
        const float4 hv = s_h[k];
        xh0 += v0[k].x * hv.x + v0[k].y * hv.y + v0[k].z * hv.z + v0[k].w * hv.w;
        xh1 += v1[k].x * hv.x + v1[k].y * hv.y + v1[k].z * hv.z + v1[k].w * hv.w;
    }

    const float r0 = x0 - xh0, r1 = x1 - xh1;
    float lr = r0 * r0 + r1 * r1;
    float lh = xh0 * xh0 + xh1 * xh1;

#pragma unroll
    for (int off = 32; off > 0; off >>= 1) {
        lr += __shfl_down(lr, off, 64);
        lh += __shfl_down(lh, off, 64);
    }
    if (lane == 0) { s_lr[wid] = lr; s_lh[wid] = lh; }
    __syncthreads();
    if (t == 0) {
        atomicAdd(&scalars[1], s_lr[0] + s_lr[1] + s_lr[2] + s_lr[3]);
        atomicAdd(&scalars[2], s_lh[0] + s_lh[1] + s_lh[2] + s_lh[3]);
    }
}

// ---------------------------------------------------------------------------
// Kernel 4: finalize scalars
// ---------------------------------------------------------------------------
__device__ __forceinline__ double block_reduce_d(double v, double* s4,
                                                 int lane, int wid)
{
#pragma unroll
    for (int off = 32; off > 0; off >>= 1) v += __shfl_down(v, off, 64);
    if (lane == 0) s4[wid] = v;
    __syncthreads();
    const double r = s4[0] + s4[1] + s4[2] + s4[3];
    __syncthreads();
    return r;
}

__global__ __launch_bounds__(256) void finalize_kernel(
    const float* __restrict__ expert_sum, const unsigned int* __restrict__ counts,
    const float* __restrict__ scalars, float* __restrict__ out)
{
    __shared__ double s4[4];
    const int t = threadIdx.x, lane = t & 63, wid = t >> 6;

    double avg[8];
    double tot = 0.0;
#pragma unroll
    for (int j = 0; j < 8; ++j) {
        avg[j] = (double)expert_sum[t + 256 * j] / (double)NROWS;
        tot += avg[j];
    }
    double denom = block_reduce_d(tot, s4, lane, wid);
    denom = (denom > 1e-8) ? denom : 1e-8;

    double entl = 0.0;
#pragma unroll
    for (int j = 0; j < 8; ++j) {
        double p = avg[j] / denom;
        p = (p > 1e-8) ? p : 1e-8;
        entl -= p * log(p);
    }
    const double entropy = block_reduce_d(entl, s4, lane, wid) / log(2048.0);

    double lowl = 0.0, deadl = 0.0;
    const float expected = (float)KTOP / (float)MEXP * (float)NROWS; // 32
#pragma unroll
    for (int j = 0; j < 8; ++j) {
        const float c = (float)counts[t + 256 * j];
        if (c <= 0.1f * expected)  lowl  += 1.0;
        if (c <= 0.01f * expected) deadl += 1.0;
    }
    const double low  = block_reduce_d(lowl, s4, lane, wid);
    const double dead = block_reduce_d(deadl, s4, lane, wid);

    if (t == 0) {
        const double captured = (double)scalars[0] / (double)NROWS;
        const double uncap    = (double)scalars[1] / (double)NROWS;
        const double recon    = (double)scalars[2] / (double)NROWS;
        out[OUT_SCAL + 0] = (float)captured;
        out[OUT_SCAL + 1] = (float)recon;
        out[OUT_SCAL + 2] = (float)uncap;
        out[OUT_SCAL + 3] = (float)entropy;
        out[OUT_SCAL + 4] = (float)(uncap + 0.01 * (1.0 - entropy));
        out[OUT_SCAL + 5] = (float)low;
        out[OUT_SCAL + 6] = (float)dead;
    }
}

// ---------------------------------------------------------------------------
extern "C" void kernel_launch(void* const* d_in, const int* in_sizes, int n_in,
                              void* d_out, int out_size, void* d_ws, size_t ws_size,
                              hipStream_t stream)
{
    const float* x = (const float*)d_in[0];
    const float* h = (const float*)d_in[1];
    const float* V = (const float*)d_in[2];
    float* out = (float*)d_out;
    char*  ws  = (char*)d_ws;

    float4*       Vt         = (float4*)ws;
    float*        expert_sum = (float*)(ws + WS_ESUM_OFF);
    unsigned int* counts     = (unsigned int*)(ws + WS_CNT_OFF);
    float*        scalars    = (float*)(ws + WS_SCAL_OFF);

    // zero accumulators (ws is poisoned 0xAA before every call)
    hipMemsetAsync(ws + WS_ESUM_OFF, 0, 16384 + 64, stream);

    transpose_v_kernel<<<dim3(64, 16), 256, 0, stream>>>((const float4*)V, Vt);
    energy_topk_kernel<<<1024, 128, 0, stream>>>(h, out, expert_sum, counts,
                                                 scalars);
    recon_kernel<<<NROWS, 256, 0, stream>>>(x, out, Vt, scalars);
    finalize_kernel<<<1, 256, 0, stream>>>(expert_sum, counts, scalars, out);
}

// Round 4
// 500.602 us; speedup vs baseline: 1.3035x; 1.2851x over previous
//
#include <hip/hip_runtime.h>

// Problem constants
#define NROWS 8192
#define DDIM  512
#define MEXP  2048
#define BDIM  4
#define KTOP  8
#define EBLK  256          // energy kernel blocks (1 per CU)

typedef unsigned long long ull;

// d_out layout (floats): h_sparse [0,262144), idx [262144,327680), 7 scalars at 327680
#define OUT_IDX     262144
#define OUT_SCAL    327680

// d_ws layout (bytes) — NO global atomics anywhere; all partials plain-stored
#define WS_VT_OFF    0u                       // 16 MiB: Vt[m][d] float4 (b-dim)
#define WS_ESP_OFF   16777216u                // 256*2048 f32  = 2 MiB
#define WS_CNTP_OFF  18874368u                // 256*2048 u32  = 2 MiB
#define WS_CAP_OFF   20971520u                // 256 f32
#define WS_LRLH_OFF  20972544u                // 8192 float2 = 64 KiB
#define WS_ES_OFF    21038080u                // 2048 f32 (reduced)
#define WS_CNT_OFF   21046272u                // 2048 u32 (reduced)

typedef __attribute__((address_space(1))) unsigned int gu32;
typedef __attribute__((address_space(3))) unsigned int lu32;

// ---------------------------------------------------------------------------
// Kernel 1: wave-per-row energy + top-8 via global_load_lds streaming.
// 256 blocks x 256 thr (4 waves); each wave streams 8 rows (32 KB LDS stage).
// All reductions: LDS atomics -> per-block partial stores. ZERO global atomics.
// ---------------------------------------------------------------------------
__global__ __launch_bounds__(256) void energy_topk_kernel(
    const float* __restrict__ h_all, float* __restrict__ out,
    float* __restrict__ esum_part, unsigned int* __restrict__ cnt_part,
    float* __restrict__ cap_part)
{
    __shared__ float4 stage[4][MEXP];     // 128 KB: full row per wave
    __shared__ float s_es[MEXP];          // 8 KB
    __shared__ unsigned int s_cnt[MEXP];  // 8 KB
    __shared__ float s_cap[4];

    const int t    = threadIdx.x;
    const int lane = t & 63;
    const int wid  = t >> 6;              // 0..3
    float4* buf = stage[wid];

    for (int j = t; j < MEXP; j += 256) { s_es[j] = 0.f; s_cnt[j] = 0u; }
    __syncthreads();

    float esum[32];
#pragma unroll
    for (int j = 0; j < 32; ++j) esum[j] = 0.f;
    float capw = 0.f;

    const int gw = blockIdx.x * 4 + wid;  // 1024 waves total

    for (int r = 0; r < 8; ++r) {
        const int n = gw * 8 + r;
        const float* grow = h_all + (size_t)n * (MEXP * BDIM);

        // 32 async 1 KB direct-to-LDS loads (32 KB in flight per wave)
#pragma unroll
        for (int i = 0; i < 32; ++i) {
            __builtin_amdgcn_global_load_lds(
                (gu32*)(grow) + lane * 4 + i * 256,
                (lu32*)((unsigned int*)buf) + i * 256,
                16, 0, 0);
        }
        __builtin_amdgcn_s_waitcnt(0x0F70);   // vmcnt(0)

        ull k[8];
#pragma unroll
        for (int j = 0; j < 8; ++j) k[j] = 0ull;

#pragma unroll
        for (int i = 0; i < 32; ++i) {
            const int m = lane + 64 * i;
            const float4 h = buf[m];          // ds_read_b128, 2-way alias free
            // bit-exact numpy f32 sequential sum (no FMA contraction)
            float e = __fadd_rn(__fadd_rn(__fadd_rn(__fmul_rn(h.x, h.x),
                                                    __fmul_rn(h.y, h.y)),
                                          __fmul_rn(h.z, h.z)),
                                __fmul_rn(h.w, h.w));
            esum[i] += e;
            ull key = ((ull)__float_as_uint(e) << 32) |
                      (ull)(0xFFFFFFFFu - (unsigned)m);
            // branchless sorted insert (descending); ties -> lower index
#pragma unroll
            for (int j = 0; j < 8; ++j) {
                const ull mx = (key > k[j]) ? key : k[j];
                const ull mn = (key > k[j]) ? k[j] : key;
                k[j] = mx;
                key  = mn;
            }
        }

        // 8 rounds of wave-wide argmax over k[0] (keys unique)
        int mym = 0;
#pragma unroll
        for (int round = 0; round < 8; ++round) {
            ull w = k[0];
#pragma unroll
            for (int off = 1; off < 64; off <<= 1) {
                const ull o = __shfl_xor(w, off, 64);
                w = (o > w) ? o : w;
            }
            const int m = (int)(0xFFFFFFFFu - (unsigned)(w & 0xFFFFFFFFull));
            if (lane == round) mym = m;
            if (lane == 0) capw += __uint_as_float((unsigned)(w >> 32));
            const bool own = (k[0] == w);
#pragma unroll
            for (int j = 0; j < 7; ++j) k[j] = own ? k[j + 1] : k[j];
            if (own) k[7] = 0ull;
        }

        if (lane < KTOP) {
            const float4 hv = buf[mym];                        // LDS gather
            ((float4*)out)[(size_t)n * KTOP + lane] = hv;      // h_sparse
            out[OUT_IDX + (size_t)n * KTOP + lane] = (float)mym;
            atomicAdd(&s_cnt[mym], 1u);                        // LDS atomic
        }
    }

    // block-level reduce: per-lane regs -> LDS (distinct addr per lane)
#pragma unroll
    for (int j = 0; j < 32; ++j)
        atomicAdd(&s_es[lane + 64 * j], esum[j]);              // ds_add_f32
    if (lane == 0) s_cap[wid] = capw;
    __syncthreads();

    // flush per-block partials with plain coalesced stores
    float*        ep = esum_part + (size_t)blockIdx.x * MEXP;
    unsigned int* cp = cnt_part  + (size_t)blockIdx.x * MEXP;
    for (int j = t; j < MEXP; j += 256) { ep[j] = s_es[j]; cp[j] = s_cnt[j]; }
    if (t == 0) cap_part[blockIdx.x] = s_cap[0] + s_cap[1] + s_cap[2] + s_cap[3];
}

// ---------------------------------------------------------------------------
// Kernel 2: transpose V (D,M,B) -> Vt (M,D,B), float4 elements over b
// ---------------------------------------------------------------------------
__global__ __launch_bounds__(256) void transpose_v_kernel(
    const float4* __restrict__ V, float4* __restrict__ Vt)
{
    __shared__ float4 tile[32][33];
    const int bx = blockIdx.x;       // m tile: 0..63
    const int by = blockIdx.y;       // d tile: 0..15
    const int tx = threadIdx.x & 31;
    const int ty = threadIdx.x >> 5; // 0..7

#pragma unroll
    for (int i = 0; i < 4; ++i) {
        const int d = by * 32 + ty + i * 8;
        const int m = bx * 32 + tx;
        tile[ty + i * 8][tx] = V[(size_t)d * MEXP + m];
    }
    __syncthreads();
#pragma unroll
    for (int i = 0; i < 4; ++i) {
        const int m = bx * 32 + ty + i * 8;
        const int d = by * 32 + tx;
        Vt[(size_t)m * DDIM + d] = tile[tx][ty + i * 8];
    }
}

// ---------------------------------------------------------------------------
// Kernel 3: x_hat per row; per-block (lr,lh) stored to ws — ZERO atomics
// ---------------------------------------------------------------------------
__global__ __launch_bounds__(256) void recon_kernel(
    const float* __restrict__ x_flat, const float* __restrict__ out_ro,
    const float4* __restrict__ Vt, float2* __restrict__ lrlh)
{
    __shared__ float4 s_h[KTOP];
    __shared__ int    s_m[KTOP];
    __shared__ float  s_lr[4], s_lh[4];

    const int n    = blockIdx.x;
    const int t    = threadIdx.x;
    const int lane = t & 63;
    const int wid  = t >> 6;

    if (t < KTOP) {
        s_m[t] = (int)out_ro[OUT_IDX + (size_t)n * KTOP + t];
        s_h[t] = ((const float4*)out_ro)[(size_t)n * KTOP + t];
    }
    __syncthreads();

    float4 v0[KTOP], v1[KTOP];
#pragma unroll
    for (int k = 0; k < KTOP; ++k) {
        const size_t o = (size_t)s_m[k] * DDIM;
        v0[k] = Vt[o + t];          // lanes -> consecutive float4: coalesced
        v1[k] = Vt[o + t + 256];
    }
    const float x0 = x_flat[(size_t)n * DDIM + t];
    const float x1 = x_flat[(size_t)n * DDIM + t + 256];

    float xh0 = 0.f, xh1 = 0.f;
#pragma unroll
    for (int k = 0; k < KTOP; ++k) {
        const float4 hv = s_h[k];
        xh0 += v0[k].x * hv.x + v0[k].y * hv.y + v0[k].z * hv.z + v0[k].w * hv.w;
        xh1 += v1[k].x * hv.x + v1[k].y * hv.y + v1[k].z * hv.z + v1[k].w * hv.w;
    }

    const float r0 = x0 - xh0, r1 = x1 - xh1;
    float lr = r0 * r0 + r1 * r1;
    float lh = xh0 * xh0 + xh1 * xh1;

#pragma unroll
    for (int off = 32; off > 0; off >>= 1) {
        lr += __shfl_down(lr, off, 64);
        lh += __shfl_down(lh, off, 64);
    }
    if (lane == 0) { s_lr[wid] = lr; s_lh[wid] = lh; }
    __syncthreads();
    if (t == 0) {
        lrlh[n] = make_float2(s_lr[0] + s_lr[1] + s_lr[2] + s_lr[3],
                              s_lh[0] + s_lh[1] + s_lh[2] + s_lh[3]);
    }
}

// ---------------------------------------------------------------------------
// Kernel 4: reduce per-block expert partials (no atomics)
// ---------------------------------------------------------------------------
__global__ __launch_bounds__(256) void reduce_expert_kernel(
    const float* __restrict__ esum_part, const unsigned int* __restrict__ cnt_part,
    float* __restrict__ expert_sum, unsigned int* __restrict__ counts)
{
    const int e = blockIdx.x * 256 + threadIdx.x;   // 8 blocks -> 2048
    float s = 0.f;
    unsigned int c = 0u;
    for (int b = 0; b < EBLK; ++b) {
        s += esum_part[(size_t)b * MEXP + e];       // coalesced across lanes
        c += cnt_part[(size_t)b * MEXP + e];
    }
    expert_sum[e] = s;
    counts[e] = c;
}

// ---------------------------------------------------------------------------
// Kernel 5: finalize scalars
// ---------------------------------------------------------------------------
__device__ __forceinline__ double block_reduce_d(double v, double* s4,
                                                 int lane, int wid)
{
#pragma unroll
    for (int off = 32; off > 0; off >>= 1) v += __shfl_down(v, off, 64);
    if (lane == 0) s4[wid] = v;
    __syncthreads();
    const double r = s4[0] + s4[1] + s4[2] + s4[3];
    __syncthreads();
    return r;
}

__global__ __launch_bounds__(256) void finalize_kernel(
    const float* __restrict__ expert_sum, const unsigned int* __restrict__ counts,
    const float* __restrict__ cap_part, const float2* __restrict__ lrlh,
    float* __restrict__ out)
{
    __shared__ double s4[4];
    const int t = threadIdx.x, lane = t & 63, wid = t >> 6;

    double avg[8];
    double tot = 0.0;
#pragma unroll
    for (int j = 0; j < 8; ++j) {
        avg[j] = (double)expert_sum[t + 256 * j] / (double)NROWS;
        tot += avg[j];
    }
    double denom = block_reduce_d(tot, s4, lane, wid);
    denom = (denom > 1e-8) ? denom : 1e-8;

    double entl = 0.0;
#pragma unroll
    for (int j = 0; j < 8; ++j) {
        double p = avg[j] / denom;
        p = (p > 1e-8) ? p : 1e-8;
        entl -= p * log(p);
    }
    const double entropy = block_reduce_d(entl, s4, lane, wid) / log(2048.0);

    double lowl = 0.0, deadl = 0.0;
    const float expected = (float)KTOP / (float)MEXP * (float)NROWS; // 32
#pragma unroll
    for (int j = 0; j < 8; ++j) {
        const float c = (float)counts[t + 256 * j];
        if (c <= 0.1f * expected)  lowl  += 1.0;
        if (c <= 0.01f * expected) deadl += 1.0;
    }
    const double low  = block_reduce_d(lowl, s4, lane, wid);
    const double dead = block_reduce_d(deadl, s4, lane, wid);

    // scalar partial sums (all plain loads; tiny)
    double capl = (double)cap_part[t];                 // exactly 256 entries
    const double capsum = block_reduce_d(capl, s4, lane, wid);

    double lrl = 0.0, lhl = 0.0;
    for (int i = t; i < NROWS; i += 256) {
        const float2 v = lrlh[i];
        lrl += (double)v.x;
        lhl += (double)v.y;
    }
    const double lrsum = block_reduce_d(lrl, s4, lane, wid);
    const double lhsum = block_reduce_d(lhl, s4, lane, wid);

    if (t == 0) {
        const double captured = capsum / (double)NROWS;
        const double uncap    = lrsum  / (double)NROWS;
        const double recon    = lhsum  / (double)NROWS;
        out[OUT_SCAL + 0] = (float)captured;
        out[OUT_SCAL + 1] = (float)recon;
        out[OUT_SCAL + 2] = (float)uncap;
        out[OUT_SCAL + 3] = (float)entropy;
        out[OUT_SCAL + 4] = (float)(uncap + 0.01 * (1.0 - entropy));
        out[OUT_SCAL + 5] = (float)low;
        out[OUT_SCAL + 6] = (float)dead;
    }
}

// ---------------------------------------------------------------------------
extern "C" void kernel_launch(void* const* d_in, const int* in_sizes, int n_in,
                              void* d_out, int out_size, void* d_ws, size_t ws_size,
                              hipStream_t stream)
{
    const float* x = (const float*)d_in[0];
    const float* h = (const float*)d_in[1];
    const float* V = (const float*)d_in[2];
    float* out = (float*)d_out;
    char*  ws  = (char*)d_ws;

    float4*       Vt         = (float4*)(ws + WS_VT_OFF);
    float*        esum_part  = (float*)(ws + WS_ESP_OFF);
    unsigned int* cnt_part   = (unsigned int*)(ws + WS_CNTP_OFF);
    float*        cap_part   = (float*)(ws + WS_CAP_OFF);
    float2*       lrlh       = (float2*)(ws + WS_LRLH_OFF);
    float*        expert_sum = (float*)(ws + WS_ES_OFF);
    unsigned int* counts     = (unsigned int*)(ws + WS_CNT_OFF);

    // no memset needed: every partial slot is fully written each call

    transpose_v_kernel<<<dim3(64, 16), 256, 0, stream>>>((const float4*)V, Vt);
    energy_topk_kernel<<<EBLK, 256, 0, stream>>>(h, out, esum_part, cnt_part,
                                                 cap_part);
    recon_kernel<<<NROWS, 256, 0, stream>>>(x, out, Vt, lrlh);
    reduce_expert_kernel<<<MEXP / 256, 256, 0, stream>>>(esum_part, cnt_part,
                                                         expert_sum, counts);
    finalize_kernel<<<1, 256, 0, stream>>>(expert_sum, counts, cap_part, lrlh,
                                           out);
}